// Round 12
// baseline (101.911 us; speedup 1.0000x reference)
//
#include <hip/hip_runtime.h>
#include <hip/hip_bf16.h>
#include <math.h>

#define N 4096
#define P 128
#define H 4
#define E 32
#define NSEG 32
#define TPB 256
#define PROJ_TASKS 192

#define LENMAX 256
#define VSTRIDE 264          // u16 units per Vt/Ps LDS row
#define NEGF -3.0e38f

typedef __attribute__((ext_vector_type(8))) short bf16x8;
typedef __attribute__((ext_vector_type(4))) float f32x4;
typedef unsigned short u16;

__device__ __forceinline__ u16 f2b(float x) {
    __hip_bfloat16 b = __float2bfloat16(x);
    return *(u16*)&b;
}

// ---------------------------------------------------------------------------
// Dispatch 1: counting sort (single block). Produces seg_rows (sorted slot ->
// original row), seg_off, and perm (original row -> sorted slot). perm lets
// proj WRITE Q/K/V in segment-sorted order so attn needs zero read
// indirection.
// ---------------------------------------------------------------------------
__global__ __launch_bounds__(TPB) void sort_kernel(const int* __restrict__ pos,
                                                   int* __restrict__ seg_rows,
                                                   int* __restrict__ seg_off,
                                                   int* __restrict__ perm) {
    __shared__ int cnt[NSEG];
    __shared__ int cur[NSEG];
    __shared__ int off[NSEG + 1];
    const int t = threadIdx.x;
    if (t < NSEG) cnt[t] = 0;
    __syncthreads();
    for (int i = t; i < N; i += TPB) atomicAdd(&cnt[pos[i]], 1);
    __syncthreads();
    if (t == 0) {
        int s = 0;
        for (int k = 0; k < NSEG; ++k) { off[k] = s; s += cnt[k]; }
        off[NSEG] = s;
    }
    __syncthreads();
    if (t <= NSEG) seg_off[t] = off[t];
    if (t < NSEG) cur[t] = off[t];
    __syncthreads();
    for (int i = t; i < N; i += TPB) {
        const int r = atomicAdd(&cur[pos[i]], 1);
        seg_rows[r] = i;
        perm[i] = r;
    }
}

// ---------------------------------------------------------------------------
// Dispatch 2: QKV projection, 64-row tiles x 3 matrices = 192 blocks.
// fp32 accumulate, bf16 store SCATTERED to sorted slot perm[row].
// ---------------------------------------------------------------------------
__global__ __launch_bounds__(TPB) void proj_kernel(
        const float* __restrict__ x,
        const float* __restrict__ Wq, const float* __restrict__ bq,
        const float* __restrict__ Wk, const float* __restrict__ bk,
        const float* __restrict__ Wv, const float* __restrict__ bv,
        const int* __restrict__ perm,
        u16* __restrict__ Qs, u16* __restrict__ Ks, u16* __restrict__ Vs) {
    __shared__ __align__(16) float sm[12288];   // 48 KB
    float* Xl = sm;           // [64][128]
    float* Wl = sm + 8192;    // [32][128]

    const int task = blockIdx.x;
    const int t = threadIdx.x;
    const int mat = task >> 6;
    const int r0  = (task & 63) * 64;
    const float* W = (mat == 0) ? Wq : (mat == 1) ? Wk : Wv;
    const float* b = (mat == 0) ? bq : (mat == 1) ? bk : bv;
    u16* y         = (mat == 0) ? Qs : (mat == 1) ? Ks : Vs;

    for (int i = t * 4; i < 64 * 128; i += TPB * 4) {
        *(float4*)(Xl + i) = *(const float4*)(x + (size_t)r0 * 128 + i);
    }

    const int tc = t & 31;
    const int tr = t >> 5;

    float4 bb = *(const float4*)(b + tc * 4);
    float4 acc[8];
#pragma unroll
    for (int r = 0; r < 8; ++r) acc[r] = bb;

    for (int kc = 0; kc < 128; kc += 32) {
        __syncthreads();
        for (int i = t * 4; i < 32 * 128; i += TPB * 4) {
            *(float4*)(Wl + i) = *(const float4*)(W + (size_t)kc * 128 + i);
        }
        __syncthreads();
#pragma unroll
        for (int k0 = 0; k0 < 32; k0 += 4) {
            float4 w0 = *(float4*)&Wl[(k0 + 0) * 128 + tc * 4];
            float4 w1 = *(float4*)&Wl[(k0 + 1) * 128 + tc * 4];
            float4 w2 = *(float4*)&Wl[(k0 + 2) * 128 + tc * 4];
            float4 w3 = *(float4*)&Wl[(k0 + 3) * 128 + tc * 4];
#pragma unroll
            for (int r = 0; r < 8; ++r) {
                float4 xv = *(float4*)&Xl[(tr * 8 + r) * 128 + kc + k0];
                acc[r].x = fmaf(xv.x, w0.x, acc[r].x);
                acc[r].y = fmaf(xv.x, w0.y, acc[r].y);
                acc[r].z = fmaf(xv.x, w0.z, acc[r].z);
                acc[r].w = fmaf(xv.x, w0.w, acc[r].w);
                acc[r].x = fmaf(xv.y, w1.x, acc[r].x);
                acc[r].y = fmaf(xv.y, w1.y, acc[r].y);
                acc[r].z = fmaf(xv.y, w1.z, acc[r].z);
                acc[r].w = fmaf(xv.y, w1.w, acc[r].w);
                acc[r].x = fmaf(xv.z, w2.x, acc[r].x);
                acc[r].y = fmaf(xv.z, w2.y, acc[r].y);
                acc[r].z = fmaf(xv.z, w2.z, acc[r].z);
                acc[r].w = fmaf(xv.z, w2.w, acc[r].w);
                acc[r].x = fmaf(xv.w, w3.x, acc[r].x);
                acc[r].y = fmaf(xv.w, w3.y, acc[r].y);
                acc[r].z = fmaf(xv.w, w3.z, acc[r].z);
                acc[r].w = fmaf(xv.w, w3.w, acc[r].w);
            }
        }
    }

    // scatter-store to sorted slots (64 perm reads/block hit L1, broadcast)
#pragma unroll
    for (int r = 0; r < 8; ++r) {
        const int dst = perm[r0 + tr * 8 + r];
        ushort4 st;
        st.x = f2b(acc[r].x); st.y = f2b(acc[r].y);
        st.z = f2b(acc[r].z); st.w = f2b(acc[r].w);
        *(ushort4*)(y + (size_t)dst * 128 + tc * 4) = st;
    }
}

// ---------------------------------------------------------------------------
// MFMA attention tile helpers — Q/K/V are SEGMENT-SORTED, so every load
// address is a linear function of indices (no seg_rows hop). All trip counts
// compile-time; invalid columns masked (p=0); clamped loads are L1 dups.
// Layouts (mfma_f32_16x16x32_bf16, m89/m91/m120):
//   A[m=lane&15][k=quad*8+j]  B[k=quad*8+j][n=lane&15]
//   C/D: col=lane&15, row=quad*4+reg
// ---------------------------------------------------------------------------
__device__ __forceinline__ void tile_qk(int tt, int beg, int len, int h,
                                        const u16* __restrict__ Qs,
                                        const u16* __restrict__ Ks,
                                        u16* __restrict__ Ps,
                                        int col, int quad, float* lrow) {
    const float scale = 0.17677669529663687f;   // 1/sqrt(32)
    const int qrow = beg + min(tt * 16 + col, len - 1);
    const bf16x8 qa = *(const bf16x8*)(Qs + (size_t)qrow * 128 + h * 32 + quad * 8);

    // 16 independent direct K loads + MFMAs (single address hop, batched)
    f32x4 S[16];
#pragma unroll
    for (int kt = 0; kt < 16; ++kt) {
        const int krow = beg + min(kt * 16 + col, len - 1);
        const bf16x8 kb = *(const bf16x8*)(Ks + (size_t)krow * 128 + h * 32 + quad * 8);
        f32x4 c = {0.f, 0.f, 0.f, 0.f};
        S[kt] = __builtin_amdgcn_mfma_f32_16x16x32_bf16(qa, kb, c, 0, 0, 0);
    }

    float mrow[4] = {NEGF, NEGF, NEGF, NEGF};
#pragma unroll
    for (int kt = 0; kt < 16; ++kt) {
        const bool kvalid = (kt * 16 + col) < len;
#pragma unroll
        for (int r = 0; r < 4; ++r) {
            const float sc = kvalid ? S[kt][r] * scale : NEGF;
            S[kt][r] = sc;
            mrow[r] = fmaxf(mrow[r], sc);
        }
    }
#pragma unroll
    for (int d = 1; d < 16; d <<= 1) {
#pragma unroll
        for (int r = 0; r < 4; ++r)
            mrow[r] = fmaxf(mrow[r], __shfl_xor(mrow[r], d));
    }
    lrow[0] = lrow[1] = lrow[2] = lrow[3] = 0.f;
#pragma unroll
    for (int kt = 0; kt < 16; ++kt) {
#pragma unroll
        for (int r = 0; r < 4; ++r) {
            const float p = __expf(S[kt][r] - mrow[r]);   // masked -> 0
            S[kt][r] = p;
            lrow[r] += p;
        }
    }
#pragma unroll
    for (int d = 1; d < 16; d <<= 1) {
#pragma unroll
        for (int r = 0; r < 4; ++r)
            lrow[r] += __shfl_xor(lrow[r], d);
    }
#pragma unroll
    for (int kt = 0; kt < 16; ++kt) {
#pragma unroll
        for (int r = 0; r < 4; ++r)
            Ps[(quad * 4 + r) * VSTRIDE + kt * 16 + col] = f2b(S[kt][r]);
    }
}

__device__ __forceinline__ void tile_pv(int tt, int beg, int len, int h,
                                        const u16* __restrict__ Vt,
                                        const u16* __restrict__ Ps,
                                        const int* __restrict__ seg_rows,
                                        float* __restrict__ out,
                                        int col, int quad, const float* lrow) {
    f32x4 o0 = {0.f, 0.f, 0.f, 0.f}, o1 = {0.f, 0.f, 0.f, 0.f};
#pragma unroll
    for (int kg = 0; kg < 8; ++kg) {
        const bf16x8 pa = *(const bf16x8*)(Ps + col * VSTRIDE + kg * 32 + quad * 8);
        const bf16x8 v0 = *(const bf16x8*)(Vt + col * VSTRIDE + kg * 32 + quad * 8);
        const bf16x8 v1 = *(const bf16x8*)(Vt + (16 + col) * VSTRIDE + kg * 32 + quad * 8);
        o0 = __builtin_amdgcn_mfma_f32_16x16x32_bf16(pa, v0, o0, 0, 0, 0);
        o1 = __builtin_amdgcn_mfma_f32_16x16x32_bf16(pa, v1, o1, 0, 0, 0);
    }
    // out scatter: the ONLY indirection left — 4 independent id loads + stores
#pragma unroll
    for (int r = 0; r < 4; ++r) {
        const int qloc = tt * 16 + quad * 4 + r;
        if (qloc < len) {
            const int orow = seg_rows[beg + qloc];
            const float inv = 1.0f / lrow[r];
            float* op = out + (size_t)orow * 128 + h * 32;
            op[col]      = o0[r] * inv;
            op[16 + col] = o1[r] * inv;
        }
    }
}

// ---------------------------------------------------------------------------
// Dispatch 3: MFMA attention. Grid (NSEG, H, 2), block 256 = 4 waves.
// All reads contiguous (sorted layout); Vt staged with vector loads from
// contiguous rows; single barrier after first tile's QK hides staging.
// ---------------------------------------------------------------------------
__global__ __launch_bounds__(TPB) void attn_kernel(const u16* __restrict__ Qs,
                                                   const u16* __restrict__ Ks,
                                                   const u16* __restrict__ Vs,
                                                   const int* __restrict__ seg_rows,
                                                   const int* __restrict__ seg_off,
                                                   float* __restrict__ out) {
    __shared__ u16 smu[VSTRIDE * (32 + 4 * 16)];   // Vt(32 rows) + 4x Ps(16 rows)

    const int s = blockIdx.x, h = blockIdx.y, z = blockIdx.z;
    const int beg = seg_off[s];
    const int len = seg_off[s + 1] - beg;
    if (z * 64 >= len) return;
    const int t = threadIdx.x, w = t >> 6;
    const int lane = t & 63, col = lane & 15, quad = lane >> 4;

    // ---- stage V transposed from CONTIGUOUS sorted rows, zero-padded ----
    u16* Vt = smu;
#pragma unroll
    for (int ii = 0; ii < 4; ++ii) {                 // 1024 = 4 * TPB slots
        const int idx = ii * TPB + t;
        const int key = idx >> 2, c = idx & 3;
        bf16x8 v = {0, 0, 0, 0, 0, 0, 0, 0};
        if (key < len)
            v = *(const bf16x8*)(Vs + (size_t)(beg + key) * 128 + h * 32 + c * 8);
#pragma unroll
        for (int j = 0; j < 8; ++j)
            Vt[(c * 8 + j) * VSTRIDE + key] = (u16)v[j];
    }
    // no barrier yet — QK/softmax below doesn't touch Vt

    u16* Ps = smu + (32 + w * 16) * VSTRIDE;

    const int tt0 = z * 4 + w;
    const bool have0 = (tt0 * 16 < len);
    float lr0[4];
    if (have0)
        tile_qk(tt0, beg, len, h, Qs, Ks, Ps, col, quad, lr0);

    __syncthreads();   // Vt ready; executed exactly once by every thread

    if (have0)
        tile_pv(tt0, beg, len, h, Vt, Ps, seg_rows, out, col, quad, lr0);

    for (int tt = tt0 + 8; tt * 16 < len; tt += 8) {
        float lr[4];
        tile_qk(tt, beg, len, h, Qs, Ks, Ps, col, quad, lr);
        tile_pv(tt, beg, len, h, Vt, Ps, seg_rows, out, col, quad, lr);
    }
}

// ---------------------------------------------------------------------------
extern "C" void kernel_launch(void* const* d_in, const int* in_sizes, int n_in,
                              void* d_out, int out_size, void* d_ws, size_t ws_size,
                              hipStream_t stream) {
    const float* inp = (const float*)d_in[0];
    const int*   pos = (const int*)d_in[1];
    const float* Wq  = (const float*)d_in[2];
    const float* bq  = (const float*)d_in[3];
    const float* Wk  = (const float*)d_in[4];
    const float* bk  = (const float*)d_in[5];
    const float* Wv  = (const float*)d_in[6];
    const float* bv  = (const float*)d_in[7];
    float* out = (float*)d_out;

    // workspace: sorted Q/K/V bf16 [N][128], then seg_rows, seg_off, perm
    u16* Qs = (u16*)d_ws;
    u16* Ks = Qs + (size_t)N * 128;
    u16* Vs = Ks + (size_t)N * 128;
    int* seg_rows = (int*)(Vs + (size_t)N * 128);
    int* seg_off  = seg_rows + N;          // NSEG+1
    int* perm     = seg_off + NSEG + 1;    // N

    sort_kernel<<<1, TPB, 0, stream>>>(pos, seg_rows, seg_off, perm);

    proj_kernel<<<PROJ_TASKS, TPB, 0, stream>>>(
        inp, Wq, bq, Wk, bk, Wv, bv, perm, Qs, Ks, Vs);

    attn_kernel<<<dim3(NSEG, H, 2), TPB, 0, stream>>>(
        Qs, Ks, Vs, seg_rows, seg_off, out);
}

// Round 13
// 90.733 us; speedup vs baseline: 1.1232x; 1.1232x over previous
//
#include <hip/hip_runtime.h>
#include <hip/hip_bf16.h>
#include <math.h>

#define N 4096
#define P 128
#define H 4
#define E 32
#define NSEG 32
#define TPB 256
#define PROJ_TASKS 192

#define VSTRIDE 264          // u16 units per Vt/Ps LDS row
#define NEGF -3.0e38f

typedef __attribute__((ext_vector_type(8))) short bf16x8;
typedef __attribute__((ext_vector_type(4))) float f32x4;
typedef unsigned short u16;

__device__ __forceinline__ u16 f2b(float x) {
    __hip_bfloat16 b = __float2bfloat16(x);
    return *(u16*)&b;
}

// ---------------------------------------------------------------------------
// Counting sort (single block, LDS atomics).
// ---------------------------------------------------------------------------
__device__ __forceinline__ void sort_phase(const int* __restrict__ pos,
                                           int* __restrict__ seg_rows,
                                           int* __restrict__ seg_off,
                                           int* sm, int t) {
    int* cnt = sm;
    int* cur = sm + NSEG;
    int* off = sm + 2 * NSEG;
    if (t < NSEG) cnt[t] = 0;
    __syncthreads();
    for (int i = t; i < N; i += TPB) atomicAdd(&cnt[pos[i]], 1);
    __syncthreads();
    if (t == 0) {
        int s = 0;
        for (int k = 0; k < NSEG; ++k) { off[k] = s; s += cnt[k]; }
        off[NSEG] = s;
    }
    __syncthreads();
    if (t <= NSEG) seg_off[t] = off[t];
    if (t < NSEG) cur[t] = off[t];
    __syncthreads();
    for (int i = t; i < N; i += TPB) {
        int r = atomicAdd(&cur[pos[i]], 1);
        seg_rows[r] = i;
    }
}

// ---------------------------------------------------------------------------
// One 64-row QKV projection tile; fp32 accumulate, bf16 store (row order).
// ---------------------------------------------------------------------------
__device__ __forceinline__ void proj_phase(int task,
                                           const float* __restrict__ x,
                                           const float* __restrict__ Wq, const float* __restrict__ bq,
                                           const float* __restrict__ Wk, const float* __restrict__ bk,
                                           const float* __restrict__ Wv, const float* __restrict__ bv,
                                           u16* __restrict__ Q, u16* __restrict__ Ko, u16* __restrict__ Vo,
                                           float* sm, int t) {
    float* Xl = sm;           // [64][128]
    float* Wl = sm + 8192;    // [32][128]

    const int mat = task >> 6;
    const int r0  = (task & 63) * 64;
    const float* W = (mat == 0) ? Wq : (mat == 1) ? Wk : Wv;
    const float* b = (mat == 0) ? bq : (mat == 1) ? bk : bv;
    u16* y         = (mat == 0) ? Q  : (mat == 1) ? Ko : Vo;

    for (int i = t * 4; i < 64 * 128; i += TPB * 4) {
        *(float4*)(Xl + i) = *(const float4*)(x + (size_t)r0 * 128 + i);
    }

    const int tc = t & 31;
    const int tr = t >> 5;

    float4 bb = *(const float4*)(b + tc * 4);
    float4 acc[8];
#pragma unroll
    for (int r = 0; r < 8; ++r) acc[r] = bb;

    for (int kc = 0; kc < 128; kc += 32) {
        __syncthreads();
        for (int i = t * 4; i < 32 * 128; i += TPB * 4) {
            *(float4*)(Wl + i) = *(const float4*)(W + (size_t)kc * 128 + i);
        }
        __syncthreads();
#pragma unroll
        for (int k0 = 0; k0 < 32; k0 += 4) {
            float4 w0 = *(float4*)&Wl[(k0 + 0) * 128 + tc * 4];
            float4 w1 = *(float4*)&Wl[(k0 + 1) * 128 + tc * 4];
            float4 w2 = *(float4*)&Wl[(k0 + 2) * 128 + tc * 4];
            float4 w3 = *(float4*)&Wl[(k0 + 3) * 128 + tc * 4];
#pragma unroll
            for (int r = 0; r < 8; ++r) {
                float4 xv = *(float4*)&Xl[(tr * 8 + r) * 128 + kc + k0];
                acc[r].x = fmaf(xv.x, w0.x, acc[r].x);
                acc[r].y = fmaf(xv.x, w0.y, acc[r].y);
                acc[r].z = fmaf(xv.x, w0.z, acc[r].z);
                acc[r].w = fmaf(xv.x, w0.w, acc[r].w);
                acc[r].x = fmaf(xv.y, w1.x, acc[r].x);
                acc[r].y = fmaf(xv.y, w1.y, acc[r].y);
                acc[r].z = fmaf(xv.y, w1.z, acc[r].z);
                acc[r].w = fmaf(xv.y, w1.w, acc[r].w);
                acc[r].x = fmaf(xv.z, w2.x, acc[r].x);
                acc[r].y = fmaf(xv.z, w2.y, acc[r].y);
                acc[r].z = fmaf(xv.z, w2.z, acc[r].z);
                acc[r].w = fmaf(xv.z, w2.w, acc[r].w);
                acc[r].x = fmaf(xv.w, w3.x, acc[r].x);
                acc[r].y = fmaf(xv.w, w3.y, acc[r].y);
                acc[r].z = fmaf(xv.w, w3.z, acc[r].z);
                acc[r].w = fmaf(xv.w, w3.w, acc[r].w);
            }
        }
    }

#pragma unroll
    for (int r = 0; r < 8; ++r) {
        ushort4 st;
        st.x = f2b(acc[r].x); st.y = f2b(acc[r].y);
        st.z = f2b(acc[r].z); st.w = f2b(acc[r].w);
        *(ushort4*)(y + (size_t)(r0 + tr * 8 + r) * 128 + tc * 4) = st;
    }
}

// ---------------------------------------------------------------------------
// Dispatch 1: block 0 sorts; blocks 1..192 do proj tiles.
// ---------------------------------------------------------------------------
__global__ __launch_bounds__(TPB) void sort_proj_kernel(
        const float* __restrict__ inp, const int* __restrict__ pos,
        const float* __restrict__ Wq, const float* __restrict__ bq,
        const float* __restrict__ Wk, const float* __restrict__ bk,
        const float* __restrict__ Wv, const float* __restrict__ bv,
        u16* __restrict__ Q, u16* __restrict__ Kb, u16* __restrict__ Vb,
        int* __restrict__ seg_rows, int* __restrict__ seg_off) {
    __shared__ __align__(16) float sm[12288];   // 48 KB
    const int b = blockIdx.x;
    const int t = threadIdx.x;
    if (b == 0) {
        sort_phase(pos, seg_rows, seg_off, (int*)sm, t);
    } else {
        proj_phase(b - 1, inp, Wq, bq, Wk, bk, Wv, bv, Q, Kb, Vb, sm, t);
    }
}

// ---------------------------------------------------------------------------
// MFMA attention body, templated on KT (number of 16-wide key tiles, 8 or
// 16). ONE tile per wave, straight-line. All trip counts compile-time.
// Layouts (mfma_f32_16x16x32_bf16, m89/m91/m120):
//   A[m=lane&15][k=quad*8+j]  B[k=quad*8+j][n=lane&15]
//   C/D: col=lane&15, row=quad*4+reg
// ---------------------------------------------------------------------------
template <int KT>
__device__ __forceinline__ void attn_body(int beg, int len, int h, int z,
                                          const u16* __restrict__ Qb,
                                          const u16* __restrict__ Kb,
                                          const u16* __restrict__ Vb,
                                          const int* __restrict__ seg_rows,
                                          float* __restrict__ out,
                                          u16* __restrict__ smu,
                                          int t, int w, int col, int quad) {
    const float scale = 0.17677669529663687f;   // 1/sqrt(32)
    u16* Vt = smu;
    u16* Ps = smu + (32 + w * 16) * VSTRIDE;

    // ---- stage KT*16 keys of V transposed (vector loads, zero-padded) ----
#pragma unroll
    for (int ii = 0; ii < KT / 4; ++ii) {            // KT*64 slots / 256 threads
        const int idx = ii * TPB + t;
        const int key = idx >> 2, c = idx & 3;
        bf16x8 v = {0, 0, 0, 0, 0, 0, 0, 0};
        if (key < len)
            v = *(const bf16x8*)(Vb + (size_t)seg_rows[beg + key] * 128 + h * 32 + c * 8);
#pragma unroll
        for (int j = 0; j < 8; ++j)
            Vt[(c * 8 + j) * VSTRIDE + key] = (u16)v[j];
    }
    // no barrier yet — QK/softmax doesn't touch Vt

    const int tt = z * 4 + w;            // ONE 16-query tile per wave
    const bool have = (tt * 16 < len);
    float lrow[4];

    if (have) {
        const int qi = beg + min(tt * 16 + col, len - 1);
        const bf16x8 qa = *(const bf16x8*)(Qb + (size_t)seg_rows[qi] * 128 + h * 32 + quad * 8);

        int krow[KT];
#pragma unroll
        for (int kt = 0; kt < KT; ++kt)
            krow[kt] = seg_rows[beg + min(kt * 16 + col, len - 1)];

        f32x4 S[KT];
#pragma unroll
        for (int kt = 0; kt < KT; ++kt) {
            const bf16x8 kb = *(const bf16x8*)(Kb + (size_t)krow[kt] * 128 + h * 32 + quad * 8);
            f32x4 c = {0.f, 0.f, 0.f, 0.f};
            S[kt] = __builtin_amdgcn_mfma_f32_16x16x32_bf16(qa, kb, c, 0, 0, 0);
        }

        float mrow[4] = {NEGF, NEGF, NEGF, NEGF};
#pragma unroll
        for (int kt = 0; kt < KT; ++kt) {
            const bool kvalid = (kt * 16 + col) < len;
#pragma unroll
            for (int r = 0; r < 4; ++r) {
                const float sc = kvalid ? S[kt][r] * scale : NEGF;
                S[kt][r] = sc;
                mrow[r] = fmaxf(mrow[r], sc);
            }
        }
#pragma unroll
        for (int d = 1; d < 16; d <<= 1) {
#pragma unroll
            for (int r = 0; r < 4; ++r)
                mrow[r] = fmaxf(mrow[r], __shfl_xor(mrow[r], d));
        }
        lrow[0] = lrow[1] = lrow[2] = lrow[3] = 0.f;
#pragma unroll
        for (int kt = 0; kt < KT; ++kt) {
#pragma unroll
            for (int r = 0; r < 4; ++r) {
                const float p = __expf(S[kt][r] - mrow[r]);   // masked -> 0
                S[kt][r] = p;
                lrow[r] += p;
            }
        }
#pragma unroll
        for (int d = 1; d < 16; d <<= 1) {
#pragma unroll
            for (int r = 0; r < 4; ++r)
                lrow[r] += __shfl_xor(lrow[r], d);
        }
#pragma unroll
        for (int kt = 0; kt < KT; ++kt) {
#pragma unroll
            for (int r = 0; r < 4; ++r)
                Ps[(quad * 4 + r) * VSTRIDE + kt * 16 + col] = f2b(S[kt][r]);
        }
    }

    __syncthreads();   // Vt ready; block-uniform path, every thread executes

    if (have) {
        f32x4 o0 = {0.f, 0.f, 0.f, 0.f}, o1 = {0.f, 0.f, 0.f, 0.f};
#pragma unroll
        for (int kg = 0; kg < KT / 2; ++kg) {
            const bf16x8 pa = *(const bf16x8*)(Ps + col * VSTRIDE + kg * 32 + quad * 8);
            const bf16x8 v0 = *(const bf16x8*)(Vt + col * VSTRIDE + kg * 32 + quad * 8);
            const bf16x8 v1 = *(const bf16x8*)(Vt + (16 + col) * VSTRIDE + kg * 32 + quad * 8);
            o0 = __builtin_amdgcn_mfma_f32_16x16x32_bf16(pa, v0, o0, 0, 0, 0);
            o1 = __builtin_amdgcn_mfma_f32_16x16x32_bf16(pa, v1, o1, 0, 0, 0);
        }
#pragma unroll
        for (int r = 0; r < 4; ++r) {
            const int qloc = tt * 16 + quad * 4 + r;
            if (qloc < len) {
                const int orow = seg_rows[beg + qloc];
                const float inv = 1.0f / lrow[r];
                float* op = out + (size_t)orow * 128 + h * 32;
                op[col]      = o0[r] * inv;
                op[16 + col] = o1[r] * inv;
            }
        }
    }
}

// ---------------------------------------------------------------------------
// Dispatch 2: MFMA attention. Grid (NSEG, H, 4), block 256 = 4 waves, one
// 16-query tile per wave. Block-uniform KT=8 fast path for len<=128.
// ---------------------------------------------------------------------------
__global__ __launch_bounds__(TPB) void attn_kernel(const u16* __restrict__ Qb,
                                                   const u16* __restrict__ Kb,
                                                   const u16* __restrict__ Vb,
                                                   const int* __restrict__ seg_rows,
                                                   const int* __restrict__ seg_off,
                                                   float* __restrict__ out) {
    __shared__ u16 smu[VSTRIDE * (32 + 4 * 16)];   // Vt(32 rows) + 4x Ps(16 rows)

    const int s = blockIdx.x, h = blockIdx.y, z = blockIdx.z;
    const int beg = seg_off[s];
    const int len = seg_off[s + 1] - beg;
    if (z * 64 >= len) return;                     // dead query range
    const int t = threadIdx.x, w = t >> 6;
    const int lane = t & 63, col = lane & 15, quad = lane >> 4;

    if (len <= 128)
        attn_body<8>(beg, len, h, z, Qb, Kb, Vb, seg_rows, out, smu, t, w, col, quad);
    else
        attn_body<16>(beg, len, h, z, Qb, Kb, Vb, seg_rows, out, smu, t, w, col, quad);
}

// ---------------------------------------------------------------------------
extern "C" void kernel_launch(void* const* d_in, const int* in_sizes, int n_in,
                              void* d_out, int out_size, void* d_ws, size_t ws_size,
                              hipStream_t stream) {
    const float* inp = (const float*)d_in[0];
    const int*   pos = (const int*)d_in[1];
    const float* Wq  = (const float*)d_in[2];
    const float* bq  = (const float*)d_in[3];
    const float* Wk  = (const float*)d_in[4];
    const float* bk  = (const float*)d_in[5];
    const float* Wv  = (const float*)d_in[6];
    const float* bv  = (const float*)d_in[7];
    float* out = (float*)d_out;

    u16* Qb = (u16*)d_ws;
    u16* Kb = Qb + (size_t)N * 128;
    u16* Vb = Kb + (size_t)N * 128;
    int* seg_rows = (int*)(Vb + (size_t)N * 128);
    int* seg_off  = seg_rows + N;          // NSEG+1

    sort_proj_kernel<<<1 + PROJ_TASKS, TPB, 0, stream>>>(
        inp, pos, Wq, bq, Wk, bk, Wv, bv, Qb, Kb, Vb, seg_rows, seg_off);

    attn_kernel<<<dim3(NSEG, H, 4), TPB, 0, stream>>>(
        Qb, Kb, Vb, seg_rows, seg_off, out);
}